// Round 2
// baseline (7603.133 us; speedup 1.0000x reference)
//
#include <hip/hip_runtime.h>
#include <stdint.h>

// Sizes: B=512 S=128 NE=8192 ED=128 DD=32 ND=8 H=512 G=2048 PL=5 IN=160

typedef __attribute__((ext_vector_type(8))) short short8;
typedef __attribute__((ext_vector_type(4))) float f32x4;

__device__ __forceinline__ unsigned short f2bf(float f) {
  union { float f; unsigned u; } v; v.f = f;
  return (unsigned short)((v.u + 0x7fffu + ((v.u >> 16) & 1u)) >> 16);
}
__device__ __forceinline__ float bf2f(unsigned short h) {
  union { unsigned u; float f; } v; v.u = ((unsigned)h) << 16;
  return v.f;
}
__device__ __forceinline__ f32x4 MFMA(short8 a, short8 b, f32x4 c) {
  return __builtin_amdgcn_mfma_f32_16x16x32_bf16(a, b, c, 0, 0, 0);
}
__device__ __forceinline__ void gl2lds16(const void* g, void* l) {
  __builtin_amdgcn_global_load_lds(
      (const __attribute__((address_space(1))) void*)g,
      (__attribute__((address_space(3))) void*)l, 16, 0, 0);
}

// ---------------- K0: gather x (embeddings) + bf16 conversions + bias sum ---
__global__ __launch_bounds__(256) void k_prep(
    const int* __restrict__ inputs, const int* __restrict__ dirs,
    const float* __restrict__ link, const float* __restrict__ dire,
    const float* __restrict__ w_ih, const float* __restrict__ w_hh,
    const float* __restrict__ W1, const float* __restrict__ W2,
    const float* __restrict__ W3, const float* __restrict__ b_ih,
    const float* __restrict__ b_hh,
    unsigned short* __restrict__ xb, unsigned short* __restrict__ wihb,
    unsigned short* __restrict__ whhb, unsigned short* __restrict__ w1b,
    unsigned short* __restrict__ w2b, unsigned short* __restrict__ w3b,
    unsigned short* __restrict__ linkb, float* __restrict__ bias_sum)
{
  int64_t e = (int64_t)blockIdx.x * 256 + threadIdx.x;
  if (e < 10485760) {            // x[s][b][k] = concat(link_emb[inputs], dir_emb[dirs])
    int ei = (int)e;
    int s = ei / 81920;
    int r = ei % 81920;
    int b = r / 160, k = r % 160;
    float v;
    if (k < 128) v = link[(int64_t)inputs[b*128 + s]*128 + k];
    else         v = dire[dirs[b*128 + s]*32 + (k - 128)];
    xb[ei] = f2bf(v);
    return;
  }
  e -= 10485760;
  if (e < 327680)  { wihb[e] = f2bf(w_ih[e]); return; }
  e -= 327680;
  if (e < 1048576) { whhb[e] = f2bf(w_hh[e]); return; }
  e -= 1048576;
  if (e < 262144)  { w1b[e] = f2bf(W1[e]); return; }
  e -= 262144;
  if (e < 262144)  { w2b[e] = f2bf(W2[e]); return; }
  e -= 262144;
  if (e < 4096)    { w3b[e] = f2bf(W3[e]); return; }
  e -= 4096;
  if (e < 1048704) { linkb[e] = f2bf(link[e]); return; }
  e -= 1048704;
  if (e < 2048)    { bias_sum[e] = b_ih[e] + b_hh[e]; return; }
}

// ---------------- K1: gates_x = x @ w_ih^T + bias_sum, written in the
// persistent kernel's fragment order: [s][bg16][u16][w4][g4][l64][r4] bf16
__global__ __launch_bounds__(256) void k_gatesx(
    const unsigned short* __restrict__ xb, const unsigned short* __restrict__ wihb,
    const float* __restrict__ bias_sum, unsigned short* __restrict__ gx)
{
  const int jt1 = blockIdx.x;   // [0,16): 32 hidden units each (== u slice)
  const int bt2 = blockIdx.y;   // [0,2):  256 batch rows each
  const int s   = blockIdx.z;   // [0,128)
  const int t = threadIdx.x, w = t >> 6, l = t & 63;

  __shared__ unsigned short Ash[16*64*8];  // [ms16][l64][8]  16KB
  __shared__ unsigned short Bsh[8*64*8];   // [ns8][l64][8]    8KB

  f32x4 acc[4][8];
#pragma unroll
  for (int ns = 0; ns < 8; ns++) {
    int dj = ns >> 2, g = ns & 3;
    int gcol = 512*g + 32*jt1 + 16*dj + (l & 15);
    float bv = bias_sum[gcol];
    f32x4 b4; b4[0] = bv; b4[1] = bv; b4[2] = bv; b4[3] = bv;
#pragma unroll
    for (int msl = 0; msl < 4; msl++) acc[msl][ns] = b4;
  }
  const unsigned short* xrow = xb + (int64_t)(s*512 + bt2*256)*160;

  for (int ch = 0; ch < 5; ch++) {   // K=160, chunks of 32
    __syncthreads();
#pragma unroll
    for (int i = 0; i < 4; i++) {    // A: 1024 slots of 16B
      int slot = t + 256*i;
      int ms = slot >> 6, ll = slot & 63;
      int row = 16*ms + (ll & 15);
      int k = 32*ch + 8*(ll >> 4);
      *(uint4*)&Ash[slot*8] = *(const uint4*)&xrow[row*160 + k];
    }
#pragma unroll
    for (int i = 0; i < 2; i++) {    // B: 512 slots
      int slot = t + 256*i;
      int ns = slot >> 6, ll = slot & 63;
      int dj = ns >> 2, g = ns & 3;
      int gcol = 512*g + 32*jt1 + 16*dj + (ll & 15);
      int k = 32*ch + 8*(ll >> 4);
      *(uint4*)&Bsh[slot*8] = *(const uint4*)&wihb[gcol*160 + k];
    }
    __syncthreads();
    short8 Bf[8];
#pragma unroll
    for (int ns = 0; ns < 8; ns++) Bf[ns] = *(short8*)&Bsh[(ns*64 + l)*8];
#pragma unroll
    for (int msl = 0; msl < 4; msl++) {
      short8 Af = *(short8*)&Ash[((4*w + msl)*64 + l)*8];
#pragma unroll
      for (int ns = 0; ns < 8; ns++)
        acc[msl][ns] = MFMA(Af, Bf[ns], acc[msl][ns]);
    }
  }
  // epilogue: scatter into persistent-kernel fragment order
#pragma unroll
  for (int msl = 0; msl < 4; msl++) {
    int ms1 = 4*w + msl;              // rows 256*bt2 + 16*ms1 = 32*bg + 16*mtp
    int bg = 8*bt2 + (ms1 >> 1);
    int mtp = ms1 & 1;
#pragma unroll
    for (int ns = 0; ns < 8; ns++) {
      int dj = ns >> 2, g = ns & 3;   // dj == hb
      int wp = 2*dj + mtp;            // wave' = 2*hb + mt
      int64_t elem = (((((int64_t)s*16 + bg)*16 + jt1)*4 + wp)*4 + g)*256 + l*4;
      f32x4 a = acc[msl][ns];
      uint2 pk;
      unsigned short* ps = (unsigned short*)&pk;
      ps[0] = f2bf(a[0]); ps[1] = f2bf(a[1]); ps[2] = f2bf(a[2]); ps[3] = f2bf(a[3]);
      *(uint2*)&gx[elem] = pk;
    }
  }
}

// ---------------- K2: persistent LSTM, all 128 steps in one launch ---------
// 256 WGs: bg = blk&15 (32 batch rows), u = blk>>4 (32 hidden units).
// Group (bg fixed, 16 u-slices) syncs per step via device-scope flag barrier;
// blk = u*16+bg keeps a group on one XCD under %8 round-robin (heuristic only).
// w_hh slice register-resident; c state register-resident; no gate exchange:
// wave w: Mtile = w&1, unit-half hb = w>>1 -> lane l owns unit j = 16*hb+(l&15),
// rows m0..m0+3 with m0 = 16*mt + 4*(l>>4); acc[g][r] = gate g, row m0+r.
__global__ __launch_bounds__(256, 1) void k_lstm_persist(
    const unsigned short* __restrict__ gx,     // [s][bg][u][w][g][l][r] bf16
    const unsigned short* __restrict__ whhb,   // [gatecol 2048][k 512] bf16
    unsigned short* __restrict__ hfrag,        // [par2][bg16][mt2][kc16][l64][8] bf16
    unsigned short* __restrict__ hfinal,       // [512][512] bf16 row-major
    unsigned int* __restrict__ barcnt,         // [16], zeroed per launch
    unsigned int* __restrict__ barflag)        // [16], zeroed per launch
{
  const int blk = blockIdx.x;
  const int bg = blk & 15, u = blk >> 4;
  const int t = threadIdx.x, w = t >> 6, l = t & 63;
  const int mt = w & 1, hb = w >> 1;

  __shared__ unsigned short hsh[2*16*64*8];   // 32KB: [mt][kc][l][8]
  __shared__ unsigned short gxsh[4096];       // 8KB:  [w][g][l][r]

  const int64_t gxWG = ((int64_t)(bg*16 + u)) * 4096;

  // prefetch gx[0] while we load weights
#pragma unroll
  for (int i = 0; i < 2; i++) {
    int slot = i*256 + t;
    gl2lds16(gx + gxWG + slot*8, gxsh + slot*8);
  }

  // resident w_hh B-fragments: B[g][kc], col = 512g+32u+16hb+(l&15), k=32kc+8*(l>>4)
  short8 B[4][16];
  {
    const int cl = l & 15, ko = 8*(l >> 4);
#pragma unroll
    for (int g = 0; g < 4; g++) {
      const unsigned short* bp = whhb + (size_t)(512*g + 32*u + 16*hb + cl)*512 + ko;
#pragma unroll
      for (int kc = 0; kc < 16; kc++)
        B[g][kc] = *(const short8*)(bp + 32*kc);
    }
  }

  float cst[4] = {0.f, 0.f, 0.f, 0.f};        // c state, register-resident
  const int j = 16*hb + (l & 15);
  const int lpb = 16*(j >> 3) + 4*(l >> 4);   // h-frag lane base (r adds 1 each)
  const int jb = j & 7;

  for (int s = 0; s < 128; s++) {
    const int rpar = s & 1, wpar = rpar ^ 1;
    // stage h_{s} (fragment-linear, contiguous 32KB block copy)
    const unsigned short* hr = hfrag + (size_t)rpar*262144 + (size_t)bg*16384;
#pragma unroll
    for (int i = 0; i < 8; i++) {
      int slot = i*256 + t;
      gl2lds16(hr + slot*8, hsh + slot*8);
    }
    __syncthreads();   // waits vmcnt(0): h stage + gx prefetch complete

    f32x4 acc[4];
#pragma unroll
    for (int g = 0; g < 4; g++) {
      uint2 raw = *(uint2*)&gxsh[((w*4 + g)*64 + l)*4];
      const unsigned short* pk = (const unsigned short*)&raw;
      f32x4 v; v[0] = bf2f(pk[0]); v[1] = bf2f(pk[1]); v[2] = bf2f(pk[2]); v[3] = bf2f(pk[3]);
      acc[g] = v;
    }
#pragma unroll
    for (int kc = 0; kc < 16; kc++) {
      short8 A = *(short8*)&hsh[((mt*16 + kc)*64 + l)*8];
#pragma unroll
      for (int g = 0; g < 4; g++) acc[g] = MFMA(A, B[g][kc], acc[g]);
    }

    unsigned short hv[4];
#pragma unroll
    for (int r = 0; r < 4; r++) {
      float gi = acc[0][r], gf = acc[1][r], gg = acc[2][r], go = acc[3][r];
      float ii = 1.f/(1.f + expf(-gi));
      float ff = 1.f/(1.f + expf(-gf));
      float g2 = tanhf(gg);
      float oo = 1.f/(1.f + expf(-go));
      float cv = ff*cst[r] + ii*g2;
      cst[r] = cv;
      hv[r] = f2bf(oo * tanhf(cv));
    }
    {   // write h_{s+1} fragment: kc = u, lane' = lpb+r, byte pos jb
      unsigned short* hw = hfrag + (size_t)wpar*262144 + ((size_t)bg*2 + mt)*8192 + (size_t)u*512;
#pragma unroll
      for (int r = 0; r < 4; r++) hw[(lpb + r)*8 + jb] = hv[r];
    }
    if (s == 127) {   // row-major final h for the MLP
      const int m0 = 16*mt + 4*(l >> 4);
      const int J = 32*u + j;
#pragma unroll
      for (int r = 0; r < 4; r++)
        hfinal[(size_t)(32*bg + m0 + r)*512 + J] = hv[r];
    }

    __threadfence();     // release h writes device-wide
    __syncthreads();     // all WG threads fenced; gxsh reads done -> safe to overwrite
    {   // prefetch gx[s+1] during barrier wait
      int sp = (s < 127) ? s + 1 : 127;
      const unsigned short* gsrc = gx + (int64_t)sp*1048576 + gxWG;
#pragma unroll
      for (int i = 0; i < 2; i++) {
        int slot = i*256 + t;
        gl2lds16(gsrc + slot*8, gxsh + slot*8);
      }
    }
    if (t == 0) {   // group barrier: 16 WGs sharing bg
      unsigned old = __hip_atomic_fetch_add(&barcnt[bg], 1u, __ATOMIC_ACQ_REL, __HIP_MEMORY_SCOPE_AGENT);
      if (old == 15u) {
        __hip_atomic_store(&barcnt[bg], 0u, __ATOMIC_RELAXED, __HIP_MEMORY_SCOPE_AGENT);
        __hip_atomic_store(&barflag[bg], (unsigned)(s + 1), __ATOMIC_RELEASE, __HIP_MEMORY_SCOPE_AGENT);
      } else {
        while (__hip_atomic_load(&barflag[bg], __ATOMIC_ACQUIRE, __HIP_MEMORY_SCOPE_AGENT) < (unsigned)(s + 1))
          __builtin_amdgcn_s_sleep(1);
      }
    }
    __syncthreads();
    __threadfence();     // acquire: invalidate stale h lines before next stage
  }
}

// ---------------- generic bf16 GEMM: C = act(A(MxK) * B(NxK)^T + bias) -----
// MODE 0: bf16 out + bias + relu;  MODE 1: f32 out + bias, cols < nreal;
// MODE 2: f32 out replicated x5 (pred_hard), row stride 40960.
template<int MODE>
__global__ __launch_bounds__(256) void k_gemm(
    const unsigned short* __restrict__ A, int lda,
    const unsigned short* __restrict__ Bm, int ldb, int nreal,
    const float* __restrict__ bias,
    void* __restrict__ outp, int ldo, int nchunks)
{
  const int bX = blockIdx.x, bY = blockIdx.y;
  const int t = threadIdx.x, w = t >> 6, l = t & 63;
  const int mw = w & 1, nw = w >> 1;
  __shared__ unsigned short Ash[4*2*64*8];
  __shared__ unsigned short Bsh[4*2*64*8];

  f32x4 acc[2][2];
  f32x4 z; z[0] = 0.f; z[1] = 0.f; z[2] = 0.f; z[3] = 0.f;
  acc[0][0] = z; acc[0][1] = z; acc[1][0] = z; acc[1][1] = z;

  for (int ch = 0; ch < nchunks; ch++) {
    __syncthreads();
#pragma unroll
    for (int i = 0; i < 2; i++) {
      int slot = t + 256*i;
      int p = slot >> 6, ll = slot & 63;
      int ms = p >> 1, ks = p & 1;
      int row = 64*bY + 16*ms + (ll & 15);
      int k = 64*ch + 32*ks + 8*(ll >> 4);
      *(uint4*)&Ash[slot*8] = *(const uint4*)&A[(int64_t)row*lda + k];
    }
#pragma unroll
    for (int i = 0; i < 2; i++) {
      int slot = t + 256*i;
      int p = slot >> 6, ll = slot & 63;
      int ns = p >> 1, ks = p & 1;
      int row = 64*bX + 16*ns + (ll & 15);
      if (row >= nreal) row = nreal - 1;   // clamp (garbage cols masked later)
      int k = 64*ch + 32*ks + 8*(ll >> 4);
      *(uint4*)&Bsh[slot*8] = *(const uint4*)&Bm[(int64_t)row*ldb + k];
    }
    __syncthreads();
#pragma unroll
    for (int ks = 0; ks < 2; ks++) {
      short8 A0 = *(short8*)&Ash[(((2*mw+0)*2 + ks)*64 + l)*8];
      short8 A1 = *(short8*)&Ash[(((2*mw+1)*2 + ks)*64 + l)*8];
      short8 B0 = *(short8*)&Bsh[(((2*nw+0)*2 + ks)*64 + l)*8];
      short8 B1 = *(short8*)&Bsh[(((2*nw+1)*2 + ks)*64 + l)*8];
      acc[0][0] = MFMA(A0, B0, acc[0][0]);
      acc[0][1] = MFMA(A0, B1, acc[0][1]);
      acc[1][0] = MFMA(A1, B0, acc[1][0]);
      acc[1][1] = MFMA(A1, B1, acc[1][1]);
    }
  }

#pragma unroll
  for (int mt = 0; mt < 2; mt++)
#pragma unroll
  for (int nt = 0; nt < 2; nt++) {
    int n = 64*bX + 32*nw + 16*nt + (l & 15);
    int rb = 64*bY + 32*mw + 16*mt + (l >> 4)*4;
    f32x4 a = acc[mt][nt];
    if (MODE == 0) {
      float bv = bias[n];
#pragma unroll
      for (int r = 0; r < 4; r++) {
        float v = a[r] + bv; v = v > 0.f ? v : 0.f;
        ((unsigned short*)outp)[(int64_t)(rb + r)*ldo + n] = f2bf(v);
      }
    } else if (MODE == 1) {
      if (n < nreal) {
        float bv = bias[n];
#pragma unroll
        for (int r = 0; r < 4; r++)
          ((float*)outp)[(int64_t)(rb + r)*ldo + n] = a[r] + bv;
      }
    } else {
#pragma unroll
      for (int r = 0; r < 4; r++) {
        float v = a[r];
        float* o = (float*)outp + (int64_t)(rb + r)*40960 + n;
#pragma unroll
        for (int p5 = 0; p5 < 5; p5++) o[p5*8192] = v;
      }
    }
  }
}

// ---------------- K4: softmax head, top-2, loss, count, query, pdr copy ----
__global__ __launch_bounds__(256) void k_head(
    const float* __restrict__ logits, const int* __restrict__ inputs,
    const int* __restrict__ goal, const int* __restrict__ ldm,
    const float* __restrict__ link, const float* __restrict__ dire,
    const float* __restrict__ pdr, unsigned short* __restrict__ qb,
    float* __restrict__ out)
{
  const int blk = blockIdx.x, t = threadIdx.x;
  __shared__ int idxsh[64][2];
  __shared__ float redf[256];
  __shared__ int redi[256];

  if (t < 64) {                       // top-2 for this block's 64 rows
    int b = 64*blk + t;
    float v[8];
#pragma unroll
    for (int i = 0; i < 8; i++) v[i] = logits[b*8 + i];
    int i0 = 0; float m0 = v[0];
#pragma unroll
    for (int i = 1; i < 8; i++) if (v[i] > m0) { m0 = v[i]; i0 = i; }
    int i1 = -1; float m1 = -3.4e38f;
#pragma unroll
    for (int i = 0; i < 8; i++) if (i != i0 && v[i] > m1) { m1 = v[i]; i1 = i; }
    idxsh[t][0] = i0; idxsh[t][1] = i1;
  }
  __syncthreads();
  {                                   // query = le + pad(0.5*(de0+de1)) (bf16)
    int rl = t >> 2, kc = (t & 3) * 32;
    int b = 64*blk + rl;
    int last = inputs[b*128 + 127];
    const float* le = link + (int64_t)last*128 + kc;
    int i0 = idxsh[rl][0], i1 = idxsh[rl][1];
    unsigned short q[32] __attribute__((aligned(16)));
#pragma unroll
    for (int k = 0; k < 32; k++) {
      float v = le[k];
      if (kc == 0) v += 0.5f*(dire[(i0+1)*32 + k] + dire[(i1+1)*32 + k]);
      q[k] = f2bf(v);
    }
    uint4* dst = (uint4*)&qb[b*128 + kc];
#pragma unroll
    for (int x = 0; x < 4; x++) dst[x] = ((uint4*)q)[x];
  }
  if (blk == 0) {                     // loss + direction_correct over all rows
    float lsum = 0.f; int csum = 0;
    for (int rr = t; rr < 512; rr += 256) {
      float v[8];
#pragma unroll
      for (int i = 0; i < 8; i++) v[i] = logits[rr*8 + i];
      float mx = v[0];
#pragma unroll
      for (int i = 1; i < 8; i++) mx = v[i] > mx ? v[i] : mx;
      float se = 0.f;
#pragma unroll
      for (int i = 0; i < 8; i++) se += expf(v[i] - mx);
      float lse = logf(se);
      int last = inputs[rr*128 + 127];
      int lbl = ldm[(int64_t)(last - 1)*8192 + goal[rr]];
      lsum += v[lbl] - mx - lse;      // ls2 == log_softmax (idempotent)
      int i0 = 0; float m0 = v[0];
#pragma unroll
      for (int i = 1; i < 8; i++) if (v[i] > m0) { m0 = v[i]; i0 = i; }
      int i1 = -1; float m1 = -3.4e38f;
#pragma unroll
      for (int i = 0; i < 8; i++) if (i != i0 && v[i] > m1) { m1 = v[i]; i1 = i; }
      if (i0 == lbl || i1 == lbl) csum++;
    }
    redf[t] = lsum; redi[t] = csum;
    __syncthreads();
    for (int o2 = 128; o2 > 0; o2 >>= 1) {
      if (t < o2) { redf[t] += redf[t + o2]; redi[t] += redi[t + o2]; }
      __syncthreads();
    }
    if (t == 0) {
      out[20992000] = -redf[0] / 512.f * 5.f;
      out[20992001] = (float)redi[0];
    }
  }
  for (int i = 0; i < 10; i++) {      // pred_d_rand passthrough
    int idx = blk*2560 + t*10 + i;
    out[20971520 + idx] = pdr[idx];
  }
}

// ---------------- host ----------------
extern "C" void kernel_launch(void* const* d_in, const int* in_sizes, int n_in,
                              void* d_out, int out_size, void* d_ws, size_t ws_size,
                              hipStream_t stream)
{
  const int* inputs = (const int*)d_in[0];
  const int* dirs   = (const int*)d_in[1];
  const int* goal   = (const int*)d_in[2];
  const int* ldm    = (const int*)d_in[3];
  const float* pdr  = (const float*)d_in[4];
  const float* link = (const float*)d_in[5];
  const float* dire = (const float*)d_in[6];
  const float* w_ih = (const float*)d_in[7];
  const float* b_ih = (const float*)d_in[8];
  const float* w_hh = (const float*)d_in[9];
  const float* b_hh = (const float*)d_in[10];
  const float* W1   = (const float*)d_in[11];
  const float* b1   = (const float*)d_in[12];
  const float* W2   = (const float*)d_in[13];
  const float* b2   = (const float*)d_in[14];
  const float* W3   = (const float*)d_in[15];
  const float* b3   = (const float*)d_in[16];
  float* out = (float*)d_out;

  char* wsp = (char*)d_ws;
  size_t off = 0;
  auto alloc = [&](size_t bytes) { char* p = wsp + off; off += (bytes + 255) & ~(size_t)255; return p; };
  unsigned short* xb    = (unsigned short*)alloc(10485760ull*2);
  unsigned short* wihb  = (unsigned short*)alloc(327680ull*2);
  unsigned short* whhb  = (unsigned short*)alloc(1048576ull*2);
  unsigned short* w1b   = (unsigned short*)alloc(262144ull*2);
  unsigned short* w2b   = (unsigned short*)alloc(262144ull*2);
  unsigned short* w3b   = (unsigned short*)alloc(4096ull*2);
  unsigned short* linkb = (unsigned short*)alloc(1048704ull*2);
  float* bias_sum       = (float*)alloc(2048ull*4);
  unsigned short* gxb   = (unsigned short*)alloc(134217728ull*2);  // 256 MB
  unsigned short* hfrag = (unsigned short*)alloc(524288ull*2);     // 2 parities
  unsigned short* hfinal= (unsigned short*)alloc(262144ull*2);
  unsigned int* barcnt  = (unsigned int*)alloc(256);
  unsigned int* barflag = (unsigned int*)alloc(256);
  unsigned short* z1b   = (unsigned short*)alloc(262144ull*2);
  unsigned short* z2b   = (unsigned short*)alloc(262144ull*2);
  float* logits         = (float*)alloc(4096ull*4);
  unsigned short* qb    = (unsigned short*)alloc(65536ull*2);

  hipMemsetAsync(hfrag, 0, 262144ull*2, stream);   // h_0 parity-0 = 0 (bf16)
  hipMemsetAsync(barcnt, 0, 512, stream);          // barcnt + barflag contiguous

  k_prep<<<52505, 256, 0, stream>>>(inputs, dirs, link, dire, w_ih, w_hh, W1, W2, W3,
                                    b_ih, b_hh, xb, wihb, whhb, w1b, w2b, w3b, linkb, bias_sum);
  k_gatesx<<<dim3(16,2,128), 256, 0, stream>>>(xb, wihb, bias_sum, gxb);
  k_lstm_persist<<<256, 256, 0, stream>>>(gxb, whhb, hfrag, hfinal, barcnt, barflag);
  k_gemm<0><<<dim3(8,8), 256, 0, stream>>>(hfinal, 512, w1b, 512, 512, b1, z1b, 512, 8);
  k_gemm<0><<<dim3(8,8), 256, 0, stream>>>(z1b, 512, w2b, 512, 512, b2, z2b, 512, 8);
  k_gemm<1><<<dim3(1,8), 256, 0, stream>>>(z2b, 512, w3b, 512, 8, b3, logits, 8, 8);
  k_head<<<8, 256, 0, stream>>>(logits, inputs, goal, ldm, link, dire, pdr, qb, out);
  k_gemm<2><<<dim3(128,8), 256, 0, stream>>>(qb, 128, linkb + 128, 128, 8192, nullptr, out, 0, 2);
}

// Round 3
// 2346.092 us; speedup vs baseline: 3.2408x; 3.2408x over previous
//
#include <hip/hip_runtime.h>
#include <stdint.h>

// Sizes: B=512 S=128 NE=8192 ED=128 DD=32 ND=8 H=512 G=2048 PL=5 IN=160

typedef __attribute__((ext_vector_type(8))) short short8;
typedef __attribute__((ext_vector_type(4))) float f32x4;

__device__ __forceinline__ unsigned short f2bf(float f) {
  union { float f; unsigned u; } v; v.f = f;
  return (unsigned short)((v.u + 0x7fffu + ((v.u >> 16) & 1u)) >> 16);
}
__device__ __forceinline__ float bf2f(unsigned short h) {
  union { unsigned u; float f; } v; v.u = ((unsigned)h) << 16;
  return v.f;
}
__device__ __forceinline__ f32x4 MFMA(short8 a, short8 b, f32x4 c) {
  return __builtin_amdgcn_mfma_f32_16x16x32_bf16(a, b, c, 0, 0, 0);
}
__device__ __forceinline__ void gl2lds16(const void* g, void* l) {
  __builtin_amdgcn_global_load_lds(
      (const __attribute__((address_space(1))) void*)g,
      (__attribute__((address_space(3))) void*)l, 16, 0, 0);
}
// write-through to coherence point (visible device-wide after vmcnt(0))
__device__ __forceinline__ void store_short_sc01(unsigned short* p, unsigned v) {
  asm volatile("global_store_short %0, %1, off sc0 sc1" :: "v"(p), "v"(v) : "memory");
}
// cache-bypassing poll load (reads coherence point; no cache invalidate)
__device__ __forceinline__ unsigned load_u32_sc01(const unsigned* p) {
  unsigned v;
  asm volatile("global_load_dword %0, %1, off sc0 sc1\n\ts_waitcnt vmcnt(0)"
               : "=v"(v) : "v"(p) : "memory");
  return v;
}
__device__ __forceinline__ void waitcnt_vm0() {
  asm volatile("s_waitcnt vmcnt(0)" ::: "memory");
}
__device__ __forceinline__ void buffer_inv_sc1() {
  asm volatile("buffer_inv sc1" ::: "memory");
}

// ---------------- K0: gather x (embeddings) + bf16 conversions + bias sum ---
__global__ __launch_bounds__(256) void k_prep(
    const int* __restrict__ inputs, const int* __restrict__ dirs,
    const float* __restrict__ link, const float* __restrict__ dire,
    const float* __restrict__ w_ih, const float* __restrict__ w_hh,
    const float* __restrict__ W1, const float* __restrict__ W2,
    const float* __restrict__ W3, const float* __restrict__ b_ih,
    const float* __restrict__ b_hh,
    unsigned short* __restrict__ xb, unsigned short* __restrict__ wihb,
    unsigned short* __restrict__ whhb, unsigned short* __restrict__ w1b,
    unsigned short* __restrict__ w2b, unsigned short* __restrict__ w3b,
    unsigned short* __restrict__ linkb, float* __restrict__ bias_sum)
{
  int64_t e = (int64_t)blockIdx.x * 256 + threadIdx.x;
  if (e < 10485760) {            // x[s][b][k] = concat(link_emb[inputs], dir_emb[dirs])
    int ei = (int)e;
    int s = ei / 81920;
    int r = ei % 81920;
    int b = r / 160, k = r % 160;
    float v;
    if (k < 128) v = link[(int64_t)inputs[b*128 + s]*128 + k];
    else         v = dire[dirs[b*128 + s]*32 + (k - 128)];
    xb[ei] = f2bf(v);
    return;
  }
  e -= 10485760;
  if (e < 327680)  { wihb[e] = f2bf(w_ih[e]); return; }
  e -= 327680;
  if (e < 1048576) { whhb[e] = f2bf(w_hh[e]); return; }
  e -= 1048576;
  if (e < 262144)  { w1b[e] = f2bf(W1[e]); return; }
  e -= 262144;
  if (e < 262144)  { w2b[e] = f2bf(W2[e]); return; }
  e -= 262144;
  if (e < 4096)    { w3b[e] = f2bf(W3[e]); return; }
  e -= 4096;
  if (e < 1048704) { linkb[e] = f2bf(link[e]); return; }
  e -= 1048704;
  if (e < 2048)    { bias_sum[e] = b_ih[e] + b_hh[e]; return; }
}

// ---------------- K1: gates_x = x @ w_ih^T + bias_sum, written in the
// persistent kernel's fragment order: [s][bg16][u16][w4][g4][l64][r4] bf16
__global__ __launch_bounds__(256) void k_gatesx(
    const unsigned short* __restrict__ xb, const unsigned short* __restrict__ wihb,
    const float* __restrict__ bias_sum, unsigned short* __restrict__ gx)
{
  const int jt1 = blockIdx.x;   // [0,16): 32 hidden units each (== u slice)
  const int bt2 = blockIdx.y;   // [0,2):  256 batch rows each
  const int s   = blockIdx.z;   // [0,128)
  const int t = threadIdx.x, w = t >> 6, l = t & 63;

  __shared__ unsigned short Ash[16*64*8];  // [ms16][l64][8]  16KB
  __shared__ unsigned short Bsh[8*64*8];   // [ns8][l64][8]    8KB

  f32x4 acc[4][8];
#pragma unroll
  for (int ns = 0; ns < 8; ns++) {
    int dj = ns >> 2, g = ns & 3;
    int gcol = 512*g + 32*jt1 + 16*dj + (l & 15);
    float bv = bias_sum[gcol];
    f32x4 b4; b4[0] = bv; b4[1] = bv; b4[2] = bv; b4[3] = bv;
#pragma unroll
    for (int msl = 0; msl < 4; msl++) acc[msl][ns] = b4;
  }
  const unsigned short* xrow = xb + (int64_t)(s*512 + bt2*256)*160;

  for (int ch = 0; ch < 5; ch++) {   // K=160, chunks of 32
    __syncthreads();
#pragma unroll
    for (int i = 0; i < 4; i++) {    // A: 1024 slots of 16B
      int slot = t + 256*i;
      int ms = slot >> 6, ll = slot & 63;
      int row = 16*ms + (ll & 15);
      int k = 32*ch + 8*(ll >> 4);
      *(uint4*)&Ash[slot*8] = *(const uint4*)&xrow[row*160 + k];
    }
#pragma unroll
    for (int i = 0; i < 2; i++) {    // B: 512 slots
      int slot = t + 256*i;
      int ns = slot >> 6, ll = slot & 63;
      int dj = ns >> 2, g = ns & 3;
      int gcol = 512*g + 32*jt1 + 16*dj + (ll & 15);
      int k = 32*ch + 8*(ll >> 4);
      *(uint4*)&Bsh[slot*8] = *(const uint4*)&wihb[gcol*160 + k];
    }
    __syncthreads();
    short8 Bf[8];
#pragma unroll
    for (int ns = 0; ns < 8; ns++) Bf[ns] = *(short8*)&Bsh[(ns*64 + l)*8];
#pragma unroll
    for (int msl = 0; msl < 4; msl++) {
      short8 Af = *(short8*)&Ash[((4*w + msl)*64 + l)*8];
#pragma unroll
      for (int ns = 0; ns < 8; ns++)
        acc[msl][ns] = MFMA(Af, Bf[ns], acc[msl][ns]);
    }
  }
  // epilogue: scatter into persistent-kernel fragment order
#pragma unroll
  for (int msl = 0; msl < 4; msl++) {
    int ms1 = 4*w + msl;              // rows 256*bt2 + 16*ms1 = 32*bg + 16*mtp
    int bg = 8*bt2 + (ms1 >> 1);
    int mtp = ms1 & 1;
#pragma unroll
    for (int ns = 0; ns < 8; ns++) {
      int dj = ns >> 2, g = ns & 3;   // dj == hb
      int wp = 2*dj + mtp;            // wave' = 2*hb + mt
      int64_t elem = (((((int64_t)s*16 + bg)*16 + jt1)*4 + wp)*4 + g)*256 + l*4;
      f32x4 a = acc[msl][ns];
      uint2 pk;
      unsigned short* ps = (unsigned short*)&pk;
      ps[0] = f2bf(a[0]); ps[1] = f2bf(a[1]); ps[2] = f2bf(a[2]); ps[3] = f2bf(a[3]);
      *(uint2*)&gx[elem] = pk;
    }
  }
}

// ---------------- K2: persistent LSTM, all 128 steps in one launch ---------
// 256 WGs: bg = blk&15 (32 batch rows), u = blk>>4 (32 hidden units).
// Cross-WG protocol (no scope fences): h stores are sc0sc1 write-through;
// release = s_waitcnt vmcnt(0); arrival = relaxed agent atomic add on a
// MONOTONIC per-group counter; poll = explicit sc0sc1 load (no inv per poll);
// after pass, ONE buffer_inv sc1 then normal cached h staging (group WGs
// share one L2 fill). Correct from any XCD (inv-then-read).
__global__ __launch_bounds__(256, 1) void k_lstm_persist(
    const unsigned short* __restrict__ gx,     // [s][bg][u][w][g][l][r] bf16
    const unsigned short* __restrict__ whhb,   // [gatecol 2048][k 512] bf16
    unsigned short* __restrict__ hfrag,        // [par2][bg16][mt2][kc16][l64][8] bf16
    unsigned short* __restrict__ hfinal,       // [512][512] bf16 row-major
    unsigned int* __restrict__ barcnt)         // [16], zeroed per launch
{
  const int blk = blockIdx.x;
  const int bg = blk & 15, u = blk >> 4;
  const int t = threadIdx.x, w = t >> 6, l = t & 63;
  const int mt = w & 1, hb = w >> 1;

  __shared__ unsigned short hsh[2*16*64*8];   // 32KB: [mt][kc][l][8]
  __shared__ unsigned short gxsh[4096];       // 8KB:  [w][g][l][r]

  const int64_t gxWG = ((int64_t)(bg*16 + u)) * 4096;

  // prefetch gx[0] while we load weights
#pragma unroll
  for (int i = 0; i < 2; i++) {
    int slot = i*256 + t;
    gl2lds16(gx + gxWG + slot*8, gxsh + slot*8);
  }

  // resident w_hh B-fragments: B[g][kc], col = 512g+32u+16hb+(l&15), k=32kc+8*(l>>4)
  short8 B[4][16];
  const int cl = l & 15, ko = 8*(l >> 4);
  {
#pragma unroll
    for (int g = 0; g < 4; g++) {
      const unsigned short* bp = whhb + (size_t)(512*g + 32*u + 16*hb + cl)*512 + ko;
#pragma unroll
      for (int kc = 0; kc < 16; kc++)
        B[g][kc] = *(const short8*)(bp + 32*kc);
    }
  }

  float cst[4] = {0.f, 0.f, 0.f, 0.f};        // c state, register-resident
  const int j = 16*hb + cl;
  const int lpb = 16*(j >> 3) + 4*(l >> 4);   // h-frag lane base (r adds 1 each)
  const int jb = j & 7;

  for (int s = 0; s < 128; s++) {
    const int rpar = s & 1, wpar = rpar ^ 1;

    if (s > 0) {   // wait for all 16 WGs of group bg to finish step s-1
      if (t == 0) {
        while (load_u32_sc01(barcnt + bg) < 16u*(unsigned)s)
          __builtin_amdgcn_s_sleep(1);
      }
      __syncthreads();
      buffer_inv_sc1();   // drop stale h lines (clean-inv: all our stores were WT)
    }

    // stage h_{s} (fragment-linear, contiguous 32KB, cached: group shares fill)
    const unsigned short* hr = hfrag + (size_t)rpar*262144 + (size_t)bg*16384;
#pragma unroll
    for (int i = 0; i < 8; i++) {
      int slot = i*256 + t;
      gl2lds16(hr + slot*8, hsh + slot*8);
    }
    waitcnt_vm0();
    __syncthreads();   // h stage + gx prefetch complete

    f32x4 acc[4];
#pragma unroll
    for (int g = 0; g < 4; g++) {
      uint2 raw = *(uint2*)&gxsh[((w*4 + g)*64 + l)*4];
      const unsigned short* pk = (const unsigned short*)&raw;
      f32x4 v; v[0] = bf2f(pk[0]); v[1] = bf2f(pk[1]); v[2] = bf2f(pk[2]); v[3] = bf2f(pk[3]);
      acc[g] = v;
    }
#pragma unroll
    for (int kc = 0; kc < 16; kc++) {
      short8 A = *(short8*)&hsh[((mt*16 + kc)*64 + l)*8];
#pragma unroll
      for (int g = 0; g < 4; g++) acc[g] = MFMA(A, B[g][kc], acc[g]);
    }

    unsigned short hv[4];
#pragma unroll
    for (int r = 0; r < 4; r++) {
      float gi = acc[0][r], gf = acc[1][r], gg = acc[2][r], go = acc[3][r];
      float ii = 1.f/(1.f + expf(-gi));
      float ff = 1.f/(1.f + expf(-gf));
      float g2 = tanhf(gg);
      float oo = 1.f/(1.f + expf(-go));
      float cv = ff*cst[r] + ii*g2;
      cst[r] = cv;
      hv[r] = f2bf(oo * tanhf(cv));
    }

    if (s < 127) {
      // write h_{s+1} fragment write-through: kc = u, lane' = lpb+r, byte pos jb
      unsigned short* hw = hfrag + (size_t)wpar*262144 + ((size_t)bg*2 + mt)*8192 + (size_t)u*512;
#pragma unroll
      for (int r = 0; r < 4; r++)
        store_short_sc01(&hw[(lpb + r)*8 + jb], (unsigned)hv[r]);
      waitcnt_vm0();     // release: sc1 stores ack from coherence point
      __syncthreads();   // whole WG's stores are globally visible
      if (t == 0)
        __hip_atomic_fetch_add(barcnt + bg, 1u, __ATOMIC_RELAXED, __HIP_MEMORY_SCOPE_AGENT);
      // prefetch gx[s+1] during the (next) barrier wait
      const unsigned short* gsrc = gx + (int64_t)(s + 1)*1048576 + gxWG;
#pragma unroll
      for (int i = 0; i < 2; i++) {
        int slot = i*256 + t;
        gl2lds16(gsrc + slot*8, gxsh + slot*8);
      }
    } else {   // row-major final h for the MLP (flushed at kernel end)
      const int m0 = 16*mt + 4*(l >> 4);
      const int J = 32*u + j;
#pragma unroll
      for (int r = 0; r < 4; r++)
        hfinal[(size_t)(32*bg + m0 + r)*512 + J] = hv[r];
    }
  }
}

// ---------------- generic bf16 GEMM: C = act(A(MxK) * B(NxK)^T + bias) -----
// MODE 0: bf16 out + bias + relu;  MODE 1: f32 out + bias, cols < nreal;
// MODE 2: f32 out replicated x5 (pred_hard), row stride 40960.
template<int MODE>
__global__ __launch_bounds__(256) void k_gemm(
    const unsigned short* __restrict__ A, int lda,
    const unsigned short* __restrict__ Bm, int ldb, int nreal,
    const float* __restrict__ bias,
    void* __restrict__ outp, int ldo, int nchunks)
{
  const int bX = blockIdx.x, bY = blockIdx.y;
  const int t = threadIdx.x, w = t >> 6, l = t & 63;
  const int mw = w & 1, nw = w >> 1;
  __shared__ unsigned short Ash[4*2*64*8];
  __shared__ unsigned short Bsh[4*2*64*8];

  f32x4 acc[2][2];
  f32x4 z; z[0] = 0.f; z[1] = 0.f; z[2] = 0.f; z[3] = 0.f;
  acc[0][0] = z; acc[0][1] = z; acc[1][0] = z; acc[1][1] = z;

  for (int ch = 0; ch < nchunks; ch++) {
    __syncthreads();
#pragma unroll
    for (int i = 0; i < 2; i++) {
      int slot = t + 256*i;
      int p = slot >> 6, ll = slot & 63;
      int ms = p >> 1, ks = p & 1;
      int row = 64*bY + 16*ms + (ll & 15);
      int k = 64*ch + 32*ks + 8*(ll >> 4);
      *(uint4*)&Ash[slot*8] = *(const uint4*)&A[(int64_t)row*lda + k];
    }
#pragma unroll
    for (int i = 0; i < 2; i++) {
      int slot = t + 256*i;
      int p = slot >> 6, ll = slot & 63;
      int ns = p >> 1, ks = p & 1;
      int row = 64*bX + 16*ns + (ll & 15);
      if (row >= nreal) row = nreal - 1;   // clamp (garbage cols masked later)
      int k = 64*ch + 32*ks + 8*(ll >> 4);
      *(uint4*)&Bsh[slot*8] = *(const uint4*)&Bm[(int64_t)row*ldb + k];
    }
    __syncthreads();
#pragma unroll
    for (int ks = 0; ks < 2; ks++) {
      short8 A0 = *(short8*)&Ash[(((2*mw+0)*2 + ks)*64 + l)*8];
      short8 A1 = *(short8*)&Ash[(((2*mw+1)*2 + ks)*64 + l)*8];
      short8 B0 = *(short8*)&Bsh[(((2*nw+0)*2 + ks)*64 + l)*8];
      short8 B1 = *(short8*)&Bsh[(((2*nw+1)*2 + ks)*64 + l)*8];
      acc[0][0] = MFMA(A0, B0, acc[0][0]);
      acc[0][1] = MFMA(A0, B1, acc[0][1]);
      acc[1][0] = MFMA(A1, B0, acc[1][0]);
      acc[1][1] = MFMA(A1, B1, acc[1][1]);
    }
  }

#pragma unroll
  for (int mt = 0; mt < 2; mt++)
#pragma unroll
  for (int nt = 0; nt < 2; nt++) {
    int n = 64*bX + 32*nw + 16*nt + (l & 15);
    int rb = 64*bY + 32*mw + 16*mt + (l >> 4)*4;
    f32x4 a = acc[mt][nt];
    if (MODE == 0) {
      float bv = bias[n];
#pragma unroll
      for (int r = 0; r < 4; r++) {
        float v = a[r] + bv; v = v > 0.f ? v : 0.f;
        ((unsigned short*)outp)[(int64_t)(rb + r)*ldo + n] = f2bf(v);
      }
    } else if (MODE == 1) {
      if (n < nreal) {
        float bv = bias[n];
#pragma unroll
        for (int r = 0; r < 4; r++)
          ((float*)outp)[(int64_t)(rb + r)*ldo + n] = a[r] + bv;
      }
    } else {
#pragma unroll
      for (int r = 0; r < 4; r++) {
        float v = a[r];
        float* o = (float*)outp + (int64_t)(rb + r)*40960 + n;
#pragma unroll
        for (int p5 = 0; p5 < 5; p5++) o[p5*8192] = v;
      }
    }
  }
}

// ---------------- K4: softmax head, top-2, loss, count, query, pdr copy ----
__global__ __launch_bounds__(256) void k_head(
    const float* __restrict__ logits, const int* __restrict__ inputs,
    const int* __restrict__ goal, const int* __restrict__ ldm,
    const float* __restrict__ link, const float* __restrict__ dire,
    const float* __restrict__ pdr, unsigned short* __restrict__ qb,
    float* __restrict__ out)
{
  const int blk = blockIdx.x, t = threadIdx.x;
  __shared__ int idxsh[64][2];
  __shared__ float redf[256];
  __shared__ int redi[256];

  if (t < 64) {                       // top-2 for this block's 64 rows
    int b = 64*blk + t;
    float v[8];
#pragma unroll
    for (int i = 0; i < 8; i++) v[i] = logits[b*8 + i];
    int i0 = 0; float m0 = v[0];
#pragma unroll
    for (int i = 1; i < 8; i++) if (v[i] > m0) { m0 = v[i]; i0 = i; }
    int i1 = -1; float m1 = -3.4e38f;
#pragma unroll
    for (int i = 0; i < 8; i++) if (i != i0 && v[i] > m1) { m1 = v[i]; i1 = i; }
    idxsh[t][0] = i0; idxsh[t][1] = i1;
  }
  __syncthreads();
  {                                   // query = le + pad(0.5*(de0+de1)) (bf16)
    int rl = t >> 2, kc = (t & 3) * 32;
    int b = 64*blk + rl;
    int last = inputs[b*128 + 127];
    const float* le = link + (int64_t)last*128 + kc;
    int i0 = idxsh[rl][0], i1 = idxsh[rl][1];
    unsigned short q[32] __attribute__((aligned(16)));
#pragma unroll
    for (int k = 0; k < 32; k++) {
      float v = le[k];
      if (kc == 0) v += 0.5f*(dire[(i0+1)*32 + k] + dire[(i1+1)*32 + k]);
      q[k] = f2bf(v);
    }
    uint4* dst = (uint4*)&qb[b*128 + kc];
#pragma unroll
    for (int x = 0; x < 4; x++) dst[x] = ((uint4*)q)[x];
  }
  if (blk == 0) {                     // loss + direction_correct over all rows
    float lsum = 0.f; int csum = 0;
    for (int rr = t; rr < 512; rr += 256) {
      float v[8];
#pragma unroll
      for (int i = 0; i < 8; i++) v[i] = logits[rr*8 + i];
      float mx = v[0];
#pragma unroll
      for (int i = 1; i < 8; i++) mx = v[i] > mx ? v[i] : mx;
      float se = 0.f;
#pragma unroll
      for (int i = 0; i < 8; i++) se += expf(v[i] - mx);
      float lse = logf(se);
      int last = inputs[rr*128 + 127];
      int lbl = ldm[(int64_t)(last - 1)*8192 + goal[rr]];
      lsum += v[lbl] - mx - lse;      // ls2 == log_softmax (idempotent)
      int i0 = 0; float m0 = v[0];
#pragma unroll
      for (int i = 1; i < 8; i++) if (v[i] > m0) { m0 = v[i]; i0 = i; }
      int i1 = -1; float m1 = -3.4e38f;
#pragma unroll
      for (int i = 0; i < 8; i++) if (i != i0 && v[i] > m1) { m1 = v[i]; i1 = i; }
      if (i0 == lbl || i1 == lbl) csum++;
    }
    redf[t] = lsum; redi[t] = csum;
    __syncthreads();
    for (int o2 = 128; o2 > 0; o2 >>= 1) {
      if (t < o2) { redf[t] += redf[t + o2]; redi[t] += redi[t + o2]; }
      __syncthreads();
    }
    if (t == 0) {
      out[20992000] = -redf[0] / 512.f * 5.f;
      out[20992001] = (float)redi[0];
    }
  }
  for (int i = 0; i < 10; i++) {      // pred_d_rand passthrough
    int idx = blk*2560 + t*10 + i;
    out[20971520 + idx] = pdr[idx];
  }
}

// ---------------- host ----------------
extern "C" void kernel_launch(void* const* d_in, const int* in_sizes, int n_in,
                              void* d_out, int out_size, void* d_ws, size_t ws_size,
                              hipStream_t stream)
{
  const int* inputs = (const int*)d_in[0];
  const int* dirs   = (const int*)d_in[1];
  const int* goal   = (const int*)d_in[2];
  const int* ldm    = (const int*)d_in[3];
  const float* pdr  = (const float*)d_in[4];
  const float* link = (const float*)d_in[5];
  const float* dire = (const float*)d_in[6];
  const float* w_ih = (const float*)d_in[7];
  const float* b_ih = (const float*)d_in[8];
  const float* w_hh = (const float*)d_in[9];
  const float* b_hh = (const float*)d_in[10];
  const float* W1   = (const float*)d_in[11];
  const float* b1   = (const float*)d_in[12];
  const float* W2   = (const float*)d_in[13];
  const float* b2   = (const float*)d_in[14];
  const float* W3   = (const float*)d_in[15];
  const float* b3   = (const float*)d_in[16];
  float* out = (float*)d_out;

  char* wsp = (char*)d_ws;
  size_t off = 0;
  auto alloc = [&](size_t bytes) { char* p = wsp + off; off += (bytes + 255) & ~(size_t)255; return p; };
  unsigned short* xb    = (unsigned short*)alloc(10485760ull*2);
  unsigned short* wihb  = (unsigned short*)alloc(327680ull*2);
  unsigned short* whhb  = (unsigned short*)alloc(1048576ull*2);
  unsigned short* w1b   = (unsigned short*)alloc(262144ull*2);
  unsigned short* w2b   = (unsigned short*)alloc(262144ull*2);
  unsigned short* w3b   = (unsigned short*)alloc(4096ull*2);
  unsigned short* linkb = (unsigned short*)alloc(1048704ull*2);
  float* bias_sum       = (float*)alloc(2048ull*4);
  unsigned short* gxb   = (unsigned short*)alloc(134217728ull*2);  // 256 MB
  unsigned short* hfrag = (unsigned short*)alloc(524288ull*2);     // 2 parities
  unsigned short* hfinal= (unsigned short*)alloc(262144ull*2);
  unsigned int* barcnt  = (unsigned int*)alloc(256);
  unsigned short* z1b   = (unsigned short*)alloc(262144ull*2);
  unsigned short* z2b   = (unsigned short*)alloc(262144ull*2);
  float* logits         = (float*)alloc(4096ull*4);
  unsigned short* qb    = (unsigned short*)alloc(65536ull*2);

  hipMemsetAsync(hfrag, 0, 262144ull*2, stream);   // h_0 parity-0 = 0 (bf16)
  hipMemsetAsync(barcnt, 0, 256, stream);          // monotonic barrier counters

  k_prep<<<52505, 256, 0, stream>>>(inputs, dirs, link, dire, w_ih, w_hh, W1, W2, W3,
                                    b_ih, b_hh, xb, wihb, whhb, w1b, w2b, w3b, linkb, bias_sum);
  k_gatesx<<<dim3(16,2,128), 256, 0, stream>>>(xb, wihb, bias_sum, gxb);
  k_lstm_persist<<<256, 256, 0, stream>>>(gxb, whhb, hfrag, hfinal, barcnt);
  k_gemm<0><<<dim3(8,8), 256, 0, stream>>>(hfinal, 512, w1b, 512, 512, b1, z1b, 512, 8);
  k_gemm<0><<<dim3(8,8), 256, 0, stream>>>(z1b, 512, w2b, 512, 512, b2, z2b, 512, 8);
  k_gemm<1><<<dim3(1,8), 256, 0, stream>>>(z2b, 512, w3b, 512, 8, b3, logits, 8, 8);
  k_head<<<8, 256, 0, stream>>>(logits, inputs, goal, ldm, link, dire, pdr, qb, out);
  k_gemm<2><<<dim3(128,8), 256, 0, stream>>>(qb, 128, linkb + 128, 128, 8192, nullptr, out, 0, 2);
}